// Round 18
// baseline (76.898 us; speedup 1.0000x reference)
//
#include <hip/hip_runtime.h>

#define TT 7
#define DD 40
#define HH 64
#define RB 128         // rows per block
#define NRT 4          // row-tiles of 16 per wave (its row-half)
#define NTH 1024       // 16 waves: 0-7 = layer 0, 8-15 = layer 1 (quarter x row-half)
#define HS 72          // u16 stride in h planes (144 B rows -> 2-way-free b128)
#define XP 44          // float stride of x rows in LDS (11 x 16B chunks)
#define L2E 1.44269504088896340736f

typedef _Float16 f16x8 __attribute__((ext_vector_type(8)));
typedef float f32x4 __attribute__((ext_vector_type(4)));

#define MFMA(acc, a, b) acc = __builtin_amdgcn_mfma_f32_16x16x32_f16(a, b, acc, 0, 0, 0)

__device__ __forceinline__ float fast_rcp(float x) { return __builtin_amdgcn_rcpf(x); }
__device__ __forceinline__ float ex2(float x) { return __builtin_amdgcn_exp2f(x); }

// Fused LSTM cell epilogue: 5 ex2 + 3 rcp. Gates pre-scaled by log2e (gate2 & c by 2log2e).
__device__ __forceinline__ float lstm_hc(float a0, float a1, float a2, float a3,
                                         float &c) {
  float A = ex2(-a0);
  float E = ex2(a2);
  float F = ex2(-a1);
  float O = ex2(-a3);
  float igg = (E - 1.f) * fast_rcp((1.f + A) * (1.f + E));   // i * g
  float fg  = fast_rcp(1.f + F);                             // f
  c = fg * c + igg;
  float C = ex2(c * (2.f * L2E));
  return (C - 1.f) * fast_rcp((1.f + O) * (1.f + C));        // o * tanh(c)
}

typedef __attribute__((address_space(3))) unsigned lds_u32_t;
typedef const __attribute__((address_space(1))) unsigned glb_u32_t;
__device__ __forceinline__ void gl_lds16(const void* g, void* l) {
  __builtin_amdgcn_global_load_lds((glb_u32_t*)g, (lds_u32_t*)l, 16, 0, 0);
}

__device__ __forceinline__ f16x8 zf() {
  f16x8 r;
  #pragma unroll
  for (int i = 0; i < 8; ++i) r[i] = (_Float16)0.f;
  return r;
}
__device__ __forceinline__ f16x8 cvt8s(const float* p, float s) {
  float4 a = *(const float4*)p, b = *(const float4*)(p + 4);
  f16x8 r;
  r[0] = (_Float16)(a.x * s); r[1] = (_Float16)(a.y * s);
  r[2] = (_Float16)(a.z * s); r[3] = (_Float16)(a.w * s);
  r[4] = (_Float16)(b.x * s); r[5] = (_Float16)(b.y * s);
  r[6] = (_Float16)(b.z * s); r[7] = (_Float16)(b.w * s);
  return r;
}
__device__ __forceinline__ f16x8 cvt8(const float* p) {
  float4 a = *(const float4*)p, b = *(const float4*)(p + 4);
  f16x8 r;
  r[0] = (_Float16)a.x; r[1] = (_Float16)a.y; r[2] = (_Float16)a.z; r[3] = (_Float16)a.w;
  r[4] = (_Float16)b.x; r[5] = (_Float16)b.y; r[6] = (_Float16)b.z; r[7] = (_Float16)b.w;
  return r;
}
__device__ __forceinline__ f16x8 pk8(float4 a, float4 b) {
  f16x8 r;
  auto p0 = __builtin_amdgcn_cvt_pkrtz(a.x, a.y);
  auto p1 = __builtin_amdgcn_cvt_pkrtz(a.z, a.w);
  auto p2 = __builtin_amdgcn_cvt_pkrtz(b.x, b.y);
  auto p3 = __builtin_amdgcn_cvt_pkrtz(b.z, b.w);
  r[0] = p0[0]; r[1] = p0[1]; r[2] = p1[0]; r[3] = p1[1];
  r[4] = p2[0]; r[5] = p2[1]; r[6] = p3[0]; r[7] = p3[1];
  return r;
}

__global__ __launch_bounds__(NTH, 1) void lstm2_r18_kernel(
    const float* __restrict__ x,
    const float* __restrict__ Wih0, const float* __restrict__ Whh0,
    const float* __restrict__ bih0, const float* __restrict__ bhh0,
    const float* __restrict__ Wih1, const float* __restrict__ Whh1,
    const float* __restrict__ bih1, const float* __restrict__ bhh1,
    const float* __restrict__ W1, const float* __restrict__ b1,
    const float* __restrict__ W2, const float* __restrict__ b2,
    float* __restrict__ out)
{
  // planes: 0,1 = h1 ping-pong; 2,3 = h2 ping-pong (all f16). 118,784 B total.
  __shared__ __align__(16) unsigned short s_h[4][RB * HS];  // 73728 B
  __shared__ __align__(16) float s_x[2][RB * XP];           // 45056 B (tail: hid f32)

  const int tid = threadIdx.x;
  const int l   = tid & 63;
  const int wv  = tid >> 6;        // 0..15
  const bool L0 = (wv < 8);        // wave role: layer 0 vs layer 1
  const int wq  = wv & 3;          // j-quarter
  const int wm  = (wv >> 2) & 1;   // row-half (64 rows)
  const int l15 = l & 15;
  const int lg  = l >> 4;
  const int jj  = wq * 16 + l15;
  const int k0l = lg * 8;
  const int blk = blockIdx.x;
  const float* xg = x + (size_t)blk * RB * (TT * DD);

  // ---- x-staging: 1408 chunks of 16B (128 rows x 11; chunk 10 of each row = pad) ----
  const int c0 = tid, c1 = 1024 + tid;
  const int r0 = c0 / 11, p0 = c0 - r0 * 11;
  const int r1 = c1 / 11, p1 = c1 - r1 * 11;
  const bool v0 = (p0 < 10);
  const bool v1 = (c1 < 1408) && (p1 < 10);
  const float* xs0 = xg + r0 * (TT * DD) + p0 * 4;
  const float* xs1 = xg + r1 * (TT * DD) + p1 * 4;
  const int d0 = wv * 256, d1 = 4096 + wv * 256;   // wave-uniform float offsets

  // ---- prologue staging: x[0] ----
  if (v0) gl_lds16(xs0, &s_x[0][d0]);
  if (v1) gl_lds16(xs1, &s_x[0][d1]);

  // ---- per-role weight fragments (shared registers): 16 frags = 64 VGPR ----
  f16x8 W[16];
  float biasv[4];
  if (L0) {
    #pragma unroll
    for (int g = 0; g < 4; ++g) {
      const float gs = (g == 2) ? 2.f * L2E : L2E;
      int n = g * 64 + jj;
      W[g]      = cvt8s(&Wih0[n * DD + k0l], gs);
      W[4 + g]  = (lg == 0) ? cvt8s(&Wih0[n * DD + 32], gs) : zf();
      W[8 + g]  = cvt8s(&Whh0[n * HH + k0l], gs);
      W[12 + g] = cvt8s(&Whh0[n * HH + 32 + k0l], gs);
      biasv[g] = (bih0[n] + bhh0[n]) * gs;
    }
  } else {
    #pragma unroll
    for (int g = 0; g < 4; ++g) {
      const float gs = (g == 2) ? 2.f * L2E : L2E;
      int n = g * 64 + jj;
      W[g]      = cvt8s(&Wih1[n * HH + k0l], gs);
      W[4 + g]  = cvt8s(&Wih1[n * HH + 32 + k0l], gs);
      W[8 + g]  = cvt8s(&Whh1[n * HH + k0l], gs);
      W[12 + g] = cvt8s(&Whh1[n * HH + 32 + k0l], gs);
      biasv[g] = (bih1[n] + bhh1[n]) * gs;
    }
  }

  float cst[NRT][4];
  #pragma unroll
  for (int rt = 0; rt < NRT; ++rt)
    #pragma unroll
    for (int r = 0; r < 4; ++r) cst[rt][r] = 0.f;

  __syncthreads();   // x[0] staged (vmcnt drained at barrier)

  #pragma unroll 1
  for (int s = 0; s < TT; ++s) {
    if (s) __syncthreads();
    if (s < TT - 1) {          // all threads stage x[s+1]
      float* xd = &s_x[(s + 1) & 1][0];
      const int so = (s + 1) * DD;
      if (v0) gl_lds16(xs0 + so, xd + d0);
      if (v1) gl_lds16(xs1 + so, xd + d1);
    }
    const int p1r = (s - 1) & 1;

    if (L0) {
      // ---- layer 0: compute h1[s] for this wave's 4 row-tiles ----
      const float* xb = &s_x[s & 1][0];
      #pragma unroll
      for (int rt = 0; rt < NRT; ++rt) {
        const int arow = wm * 64 + rt * 16 + l15;
        const float* xr = xb + arow * XP;
        f16x8 xh = pk8(*(const float4*)(xr + k0l), *(const float4*)(xr + k0l + 4));
        f16x8 xm = xh;
        if (lg == 0) xm = pk8(*(const float4*)(xr + 32), *(const float4*)(xr + 36));

        f32x4 acc[4];
        #pragma unroll
        for (int g = 0; g < 4; ++g)
          acc[g] = (f32x4){biasv[g], biasv[g], biasv[g], biasv[g]};

        __builtin_amdgcn_s_setprio(1);
        #pragma unroll
        for (int g = 0; g < 4; ++g) MFMA(acc[g], xh, W[g]);
        #pragma unroll
        for (int g = 0; g < 4; ++g) MFMA(acc[g], xm, W[4 + g]);
        if (s) {
          const unsigned short* hp = &s_h[p1r][arow * HS + k0l];
          f16x8 h1a = *(const f16x8*)hp;
          f16x8 h1b = *(const f16x8*)(hp + 32);
          #pragma unroll
          for (int g = 0; g < 4; ++g) MFMA(acc[g], h1a, W[8 + g]);
          #pragma unroll
          for (int g = 0; g < 4; ++g) MFMA(acc[g], h1b, W[12 + g]);
        }
        __builtin_amdgcn_s_setprio(0);

        #pragma unroll
        for (int r = 0; r < 4; ++r) {
          float h = lstm_hc(acc[0][r], acc[1][r], acc[2][r], acc[3][r], cst[rt][r]);
          s_h[s & 1][(wm * 64 + rt * 16 + lg * 4 + r) * HS + jj] =
              __builtin_bit_cast(unsigned short, (_Float16)h);
        }
      }
    } else if (s) {
      // ---- layer 1: compute h2[s-1] for this wave's 4 row-tiles ----
      #pragma unroll
      for (int rt = 0; rt < NRT; ++rt) {
        const int arow = wm * 64 + rt * 16 + l15;
        const unsigned short* hp = &s_h[p1r][arow * HS + k0l];
        f16x8 h1a = *(const f16x8*)hp;
        f16x8 h1b = *(const f16x8*)(hp + 32);

        f32x4 acc[4];
        #pragma unroll
        for (int g = 0; g < 4; ++g)
          acc[g] = (f32x4){biasv[g], biasv[g], biasv[g], biasv[g]};

        __builtin_amdgcn_s_setprio(1);
        #pragma unroll
        for (int g = 0; g < 4; ++g) MFMA(acc[g], h1a, W[g]);
        #pragma unroll
        for (int g = 0; g < 4; ++g) MFMA(acc[g], h1b, W[4 + g]);
        if (s >= 2) {
          const unsigned short* qp = &s_h[2 + (s & 1)][arow * HS + k0l];
          f16x8 q0 = *(const f16x8*)qp;
          f16x8 q1 = *(const f16x8*)(qp + 32);
          #pragma unroll
          for (int g = 0; g < 4; ++g) MFMA(acc[g], q0, W[8 + g]);
          #pragma unroll
          for (int g = 0; g < 4; ++g) MFMA(acc[g], q1, W[12 + g]);
        }
        __builtin_amdgcn_s_setprio(0);

        #pragma unroll
        for (int r = 0; r < 4; ++r) {
          float h = lstm_hc(acc[0][r], acc[1][r], acc[2][r], acc[3][r], cst[rt][r]);
          s_h[2 + p1r][(wm * 64 + rt * 16 + lg * 4 + r) * HS + jj] =
              __builtin_bit_cast(unsigned short, (_Float16)h);
        }
      }
    }
  }

  // ---- final interval: L1 waves compute h2[6] -> f16 plane 1 ----
  __syncthreads();
  if (!L0) {
    #pragma unroll
    for (int rt = 0; rt < NRT; ++rt) {
      const int arow = wm * 64 + rt * 16 + l15;
      const unsigned short* hp = &s_h[0][arow * HS + k0l];   // h1[6] (6&1=0)
      f16x8 h1a = *(const f16x8*)hp;
      f16x8 h1b = *(const f16x8*)(hp + 32);
      const unsigned short* qp = &s_h[3][arow * HS + k0l];   // h2[5] (2+(5&1)=3)
      f16x8 q0 = *(const f16x8*)qp;
      f16x8 q1 = *(const f16x8*)(qp + 32);
      f32x4 acc[4];
      #pragma unroll
      for (int g = 0; g < 4; ++g)
        acc[g] = (f32x4){biasv[g], biasv[g], biasv[g], biasv[g]};
      __builtin_amdgcn_s_setprio(1);
      #pragma unroll
      for (int g = 0; g < 4; ++g) MFMA(acc[g], h1a, W[g]);
      #pragma unroll
      for (int g = 0; g < 4; ++g) MFMA(acc[g], h1b, W[4 + g]);
      #pragma unroll
      for (int g = 0; g < 4; ++g) MFMA(acc[g], q0, W[8 + g]);
      #pragma unroll
      for (int g = 0; g < 4; ++g) MFMA(acc[g], q1, W[12 + g]);
      __builtin_amdgcn_s_setprio(0);
      #pragma unroll
      for (int r = 0; r < 4; ++r) {
        float h = lstm_hc(acc[0][r], acc[1][r], acc[2][r], acc[3][r], cst[rt][r]);
        s_h[1][(wm * 64 + rt * 16 + lg * 4 + r) * HS + jj] =
            __builtin_bit_cast(unsigned short, (_Float16)h);
      }
    }
  }
  __syncthreads();

  // ---- FC head via MFMA: hid = relu(h2 @ W1^T + b1) ----
  {
    const int twv = wv >> 1;       // row-tile 0..7
    const int fh  = wv & 1;        // n-half 0..1
    const unsigned short* ap = &s_h[1][(twv * 16 + l15) * HS + k0l];
    f16x8 A0 = *(const f16x8*)ap;
    f16x8 A1 = *(const f16x8*)(ap + 32);
    int n = fh * 16 + l15;
    f16x8 Bf0 = cvt8(&W1[n * 64 + k0l]);          // global, L2-hot
    f16x8 Bf1 = cvt8(&W1[n * 64 + 32 + k0l]);
    float bb = b1[n];
    f32x4 accf = (f32x4){bb, bb, bb, bb};
    MFMA(accf, A0, Bf0);
    MFMA(accf, A1, Bf1);
    float* hid = &s_x[0][0];   // [128][36] f32 (x buffers dead)
    #pragma unroll
    for (int r = 0; r < 4; ++r)
      hid[(twv * 16 + lg * 4 + r) * 36 + fh * 16 + l15] = fmaxf(accf[r], 0.f);
  }
  __syncthreads();
  if (tid < RB) {
    const float* hid = &s_x[0][0];
    float a = b2[0];
    #pragma unroll
    for (int kq = 0; kq < 8; ++kq) {
      float4 hv = *(const float4*)&hid[tid * 36 + kq * 4];
      float4 wv4 = *(const float4*)&W2[kq * 4];
      a += hv.x * wv4.x + hv.y * wv4.y + hv.z * wv4.z + hv.w * wv4.w;
    }
    out[blk * RB + tid] = a;
  }
}

extern "C" void kernel_launch(void* const* d_in, const int* in_sizes, int n_in,
                              void* d_out, int out_size, void* d_ws, size_t ws_size,
                              hipStream_t stream) {
  const float* x    = (const float*)d_in[0];
  const float* Wih0 = (const float*)d_in[1];
  const float* Whh0 = (const float*)d_in[2];
  const float* bih0 = (const float*)d_in[3];
  const float* bhh0 = (const float*)d_in[4];
  const float* Wih1 = (const float*)d_in[5];
  const float* Whh1 = (const float*)d_in[6];
  const float* bih1 = (const float*)d_in[7];
  const float* bhh1 = (const float*)d_in[8];
  const float* W1   = (const float*)d_in[9];
  const float* b1   = (const float*)d_in[10];
  const float* W2   = (const float*)d_in[11];
  const float* b2   = (const float*)d_in[12];
  float* out = (float*)d_out;

  const int Btot = in_sizes[0] / (TT * DD);   // 32768
  dim3 grid(Btot / RB), block(NTH);           // 256 blocks = 1/CU, 16 waves = 4/SIMD
  lstm2_r18_kernel<<<grid, block, 0, stream>>>(
      x, Wih0, Whh0, bih0, bhh0, Wih1, Whh1, bih1, bhh1, W1, b1, W2, b2, out);
}

// Round 19
// 69.212 us; speedup vs baseline: 1.1111x; 1.1111x over previous
//
#include <hip/hip_runtime.h>

#define TT 7
#define DD 40
#define HH 64
#define RB 64          // rows per block
#define NRT 4          // row-tiles of 16 per wave (all rows, one layer)
#define NTH 512        // 8 waves: 0-3 = layer 0 (j-quarters), 4-7 = layer 1
#define HS 72          // u16 stride in h planes (144 B rows -> 2-way-free b128)
#define XP 44          // float stride of x rows in LDS (11 x 16B chunks)
#define L2E 1.44269504088896340736f

typedef _Float16 f16x8 __attribute__((ext_vector_type(8)));
typedef float f32x4 __attribute__((ext_vector_type(4)));

// v-form MFMA: all operands in arch VGPRs -> no mandatory AGPR use, no even-split.
// Hazard discipline (inline asm bypasses compiler MFMA hazard recognizer):
//   NOPS_PRE  before a cluster (VALU write -> MFMA SrcC read: 2 states)
//   NOPS_POST after a cluster  (MFMA write -> VALU read of D: <=18 states)
#define MFMA(acc, a, b) \
  asm volatile("v_mfma_f32_16x16x32_f16 %0, %1, %2, %0" : "+v"(acc) : "v"(a), "v"(b))
#define NOPS_PRE()  asm volatile("s_nop 1")
#define NOPS_POST() asm volatile("s_nop 7\n\ts_nop 7\n\ts_nop 1")

__device__ __forceinline__ float fast_rcp(float x) { return __builtin_amdgcn_rcpf(x); }
__device__ __forceinline__ float ex2(float x) { return __builtin_amdgcn_exp2f(x); }

// Fused LSTM cell epilogue: 5 ex2 + 3 rcp. Gates pre-scaled by log2e (gate2 & c by 2log2e).
__device__ __forceinline__ float lstm_hc(float a0, float a1, float a2, float a3,
                                         float &c) {
  float A = ex2(-a0);
  float E = ex2(a2);
  float F = ex2(-a1);
  float O = ex2(-a3);
  float igg = (E - 1.f) * fast_rcp((1.f + A) * (1.f + E));   // i * g
  float fg  = fast_rcp(1.f + F);                             // f
  c = fg * c + igg;
  float C = ex2(c * (2.f * L2E));
  return (C - 1.f) * fast_rcp((1.f + O) * (1.f + C));        // o * tanh(c)
}

typedef __attribute__((address_space(3))) unsigned lds_u32_t;
typedef const __attribute__((address_space(1))) unsigned glb_u32_t;
__device__ __forceinline__ void gl_lds16(const void* g, void* l) {
  __builtin_amdgcn_global_load_lds((glb_u32_t*)g, (lds_u32_t*)l, 16, 0, 0);
}

__device__ __forceinline__ f16x8 zf() {
  f16x8 r;
  #pragma unroll
  for (int i = 0; i < 8; ++i) r[i] = (_Float16)0.f;
  return r;
}
__device__ __forceinline__ f16x8 cvt8s(const float* p, float s) {
  float4 a = *(const float4*)p, b = *(const float4*)(p + 4);
  f16x8 r;
  r[0] = (_Float16)(a.x * s); r[1] = (_Float16)(a.y * s);
  r[2] = (_Float16)(a.z * s); r[3] = (_Float16)(a.w * s);
  r[4] = (_Float16)(b.x * s); r[5] = (_Float16)(b.y * s);
  r[6] = (_Float16)(b.z * s); r[7] = (_Float16)(b.w * s);
  return r;
}
__device__ __forceinline__ f16x8 cvt8(const float* p) {
  float4 a = *(const float4*)p, b = *(const float4*)(p + 4);
  f16x8 r;
  r[0] = (_Float16)a.x; r[1] = (_Float16)a.y; r[2] = (_Float16)a.z; r[3] = (_Float16)a.w;
  r[4] = (_Float16)b.x; r[5] = (_Float16)b.y; r[6] = (_Float16)b.z; r[7] = (_Float16)b.w;
  return r;
}
__device__ __forceinline__ f16x8 pk8(float4 a, float4 b) {
  f16x8 r;
  auto p0 = __builtin_amdgcn_cvt_pkrtz(a.x, a.y);
  auto p1 = __builtin_amdgcn_cvt_pkrtz(a.z, a.w);
  auto p2 = __builtin_amdgcn_cvt_pkrtz(b.x, b.y);
  auto p3 = __builtin_amdgcn_cvt_pkrtz(b.z, b.w);
  r[0] = p0[0]; r[1] = p0[1]; r[2] = p1[0]; r[3] = p1[1];
  r[4] = p2[0]; r[5] = p2[1]; r[6] = p3[0]; r[7] = p3[1];
  return r;
}

__global__ __launch_bounds__(NTH, 4) void lstm2_r19_kernel(
    const float* __restrict__ x,
    const float* __restrict__ Wih0, const float* __restrict__ Whh0,
    const float* __restrict__ bih0, const float* __restrict__ bhh0,
    const float* __restrict__ Wih1, const float* __restrict__ Whh1,
    const float* __restrict__ bih1, const float* __restrict__ bhh1,
    const float* __restrict__ W1, const float* __restrict__ b1,
    const float* __restrict__ W2, const float* __restrict__ b2,
    float* __restrict__ out)
{
  // 59,392 B per block -> 2 independent blocks/CU (118,784 <= 160 KiB) if regs fit.
  __shared__ __align__(16) unsigned short s_h[4][RB * HS];  // 36864 B
  __shared__ __align__(16) float s_x[2][RB * XP];           // 22528 B (tail: hid f32)

  const int tid = threadIdx.x;
  const int l   = tid & 63;
  const int wv  = tid >> 6;        // 0..7
  const bool L0 = (wv < 4);        // wave role: layer 0 vs layer 1
  const int l15 = l & 15;
  const int lg  = l >> 4;
  const int jj  = (wv & 3) * 16 + l15;
  const int k0l = lg * 8;
  const int blk = blockIdx.x;
  const float* xg = x + (size_t)blk * RB * (TT * DD);

  // ---- x-staging: 704 chunks of 16B (64 rows x 11; chunk p=10 of each row = pad) ----
  const int c0 = tid, c1 = 512 + tid;
  const int r0 = c0 / 11, p0 = c0 - r0 * 11;
  const int r1 = c1 / 11, p1 = c1 - r1 * 11;
  const bool v0 = (p0 < 10);
  const bool v1 = (c1 < 704) && (p1 < 10);
  const float* xs0 = xg + r0 * (TT * DD) + p0 * 4;
  const float* xs1 = xg + r1 * (TT * DD) + p1 * 4;
  const int d0 = wv * 256, d1 = 2048 + wv * 256;   // wave-uniform float offsets

  // ---- prologue staging: x[0] ----
  if (v0) gl_lds16(xs0, &s_x[0][d0]);
  if (v1) gl_lds16(xs1, &s_x[0][d1]);

  // ---- per-role weight fragments (shared registers): 16 frags = 64 VGPR ----
  f16x8 W[16];
  float biasv[4];
  if (L0) {
    #pragma unroll
    for (int g = 0; g < 4; ++g) {
      const float gs = (g == 2) ? 2.f * L2E : L2E;
      int n = g * 64 + jj;
      W[g]      = cvt8s(&Wih0[n * DD + k0l], gs);
      W[4 + g]  = (lg == 0) ? cvt8s(&Wih0[n * DD + 32], gs) : zf();
      W[8 + g]  = cvt8s(&Whh0[n * HH + k0l], gs);
      W[12 + g] = cvt8s(&Whh0[n * HH + 32 + k0l], gs);
      biasv[g] = (bih0[n] + bhh0[n]) * gs;
    }
  } else {
    #pragma unroll
    for (int g = 0; g < 4; ++g) {
      const float gs = (g == 2) ? 2.f * L2E : L2E;
      int n = g * 64 + jj;
      W[g]      = cvt8s(&Wih1[n * HH + k0l], gs);
      W[4 + g]  = cvt8s(&Wih1[n * HH + 32 + k0l], gs);
      W[8 + g]  = cvt8s(&Whh1[n * HH + k0l], gs);
      W[12 + g] = cvt8s(&Whh1[n * HH + 32 + k0l], gs);
      biasv[g] = (bih1[n] + bhh1[n]) * gs;
    }
  }

  float cst[NRT][4];
  #pragma unroll
  for (int rt = 0; rt < NRT; ++rt)
    #pragma unroll
    for (int r = 0; r < 4; ++r) cst[rt][r] = 0.f;

  __syncthreads();   // x[0] staged (vmcnt drained at barrier)

  #pragma unroll 1
  for (int s = 0; s < TT; ++s) {
    if (s) __syncthreads();
    if (s < TT - 1) {          // stage x[s+1] into the other buffer
      float* xd = &s_x[(s + 1) & 1][0];
      const int so = (s + 1) * DD;
      if (v0) gl_lds16(xs0 + so, xd + d0);
      if (v1) gl_lds16(xs1 + so, xd + d1);
    }
    const int p1r = (s - 1) & 1;

    if (L0) {
      // ---- layer 0: compute h1[s] for all 4 row-tiles ----
      const float* xb = &s_x[s & 1][0];
      #pragma unroll
      for (int rt = 0; rt < NRT; ++rt) {
        const int arow = rt * 16 + l15;
        const float* xr = xb + arow * XP;
        f16x8 xh = pk8(*(const float4*)(xr + k0l), *(const float4*)(xr + k0l + 4));
        f16x8 xm = xh;
        if (lg == 0) xm = pk8(*(const float4*)(xr + 32), *(const float4*)(xr + 36));

        f32x4 acc[4];
        #pragma unroll
        for (int g = 0; g < 4; ++g)
          acc[g] = (f32x4){biasv[g], biasv[g], biasv[g], biasv[g]};

        __builtin_amdgcn_s_setprio(1);
        NOPS_PRE();
        #pragma unroll
        for (int g = 0; g < 4; ++g) MFMA(acc[g], xh, W[g]);
        #pragma unroll
        for (int g = 0; g < 4; ++g) MFMA(acc[g], xm, W[4 + g]);
        if (s) {
          const unsigned short* hp = &s_h[p1r][arow * HS + k0l];
          f16x8 h1a = *(const f16x8*)hp;
          f16x8 h1b = *(const f16x8*)(hp + 32);
          #pragma unroll
          for (int g = 0; g < 4; ++g) MFMA(acc[g], h1a, W[8 + g]);
          #pragma unroll
          for (int g = 0; g < 4; ++g) MFMA(acc[g], h1b, W[12 + g]);
        }
        NOPS_POST();
        __builtin_amdgcn_s_setprio(0);

        #pragma unroll
        for (int r = 0; r < 4; ++r) {
          float h = lstm_hc(acc[0][r], acc[1][r], acc[2][r], acc[3][r], cst[rt][r]);
          s_h[s & 1][(rt * 16 + lg * 4 + r) * HS + jj] =
              __builtin_bit_cast(unsigned short, (_Float16)h);
        }
      }
    } else if (s) {
      // ---- layer 1: compute h2[s-1] for all 4 row-tiles ----
      #pragma unroll
      for (int rt = 0; rt < NRT; ++rt) {
        const int arow = rt * 16 + l15;
        const unsigned short* hp = &s_h[p1r][arow * HS + k0l];
        f16x8 h1a = *(const f16x8*)hp;
        f16x8 h1b = *(const f16x8*)(hp + 32);

        f32x4 acc[4];
        #pragma unroll
        for (int g = 0; g < 4; ++g)
          acc[g] = (f32x4){biasv[g], biasv[g], biasv[g], biasv[g]};

        __builtin_amdgcn_s_setprio(1);
        NOPS_PRE();
        #pragma unroll
        for (int g = 0; g < 4; ++g) MFMA(acc[g], h1a, W[g]);
        #pragma unroll
        for (int g = 0; g < 4; ++g) MFMA(acc[g], h1b, W[4 + g]);
        if (s >= 2) {
          const unsigned short* qp = &s_h[2 + (s & 1)][arow * HS + k0l];
          f16x8 q0 = *(const f16x8*)qp;
          f16x8 q1 = *(const f16x8*)(qp + 32);
          #pragma unroll
          for (int g = 0; g < 4; ++g) MFMA(acc[g], q0, W[8 + g]);
          #pragma unroll
          for (int g = 0; g < 4; ++g) MFMA(acc[g], q1, W[12 + g]);
        }
        NOPS_POST();
        __builtin_amdgcn_s_setprio(0);

        #pragma unroll
        for (int r = 0; r < 4; ++r) {
          float h = lstm_hc(acc[0][r], acc[1][r], acc[2][r], acc[3][r], cst[rt][r]);
          s_h[2 + p1r][(rt * 16 + lg * 4 + r) * HS + jj] =
              __builtin_bit_cast(unsigned short, (_Float16)h);
        }
      }
    }
  }

  // ---- final interval: L1 waves compute h2[6] -> f16 plane 1 ----
  __syncthreads();
  if (!L0) {
    #pragma unroll
    for (int rt = 0; rt < NRT; ++rt) {
      const int arow = rt * 16 + l15;
      const unsigned short* hp = &s_h[0][arow * HS + k0l];   // h1[6] (6&1=0)
      f16x8 h1a = *(const f16x8*)hp;
      f16x8 h1b = *(const f16x8*)(hp + 32);
      const unsigned short* qp = &s_h[3][arow * HS + k0l];   // h2[5] (2+(5&1)=3)
      f16x8 q0 = *(const f16x8*)qp;
      f16x8 q1 = *(const f16x8*)(qp + 32);
      f32x4 acc[4];
      #pragma unroll
      for (int g = 0; g < 4; ++g)
        acc[g] = (f32x4){biasv[g], biasv[g], biasv[g], biasv[g]};
      __builtin_amdgcn_s_setprio(1);
      NOPS_PRE();
      #pragma unroll
      for (int g = 0; g < 4; ++g) MFMA(acc[g], h1a, W[g]);
      #pragma unroll
      for (int g = 0; g < 4; ++g) MFMA(acc[g], h1b, W[4 + g]);
      #pragma unroll
      for (int g = 0; g < 4; ++g) MFMA(acc[g], q0, W[8 + g]);
      #pragma unroll
      for (int g = 0; g < 4; ++g) MFMA(acc[g], q1, W[12 + g]);
      NOPS_POST();
      __builtin_amdgcn_s_setprio(0);
      #pragma unroll
      for (int r = 0; r < 4; ++r) {
        float h = lstm_hc(acc[0][r], acc[1][r], acc[2][r], acc[3][r], cst[rt][r]);
        s_h[1][(rt * 16 + lg * 4 + r) * HS + jj] =
            __builtin_bit_cast(unsigned short, (_Float16)h);
      }
    }
  }
  __syncthreads();

  // ---- FC head via MFMA: hid = relu(h2 @ W1^T + b1) ----
  {
    const int twv = wv >> 1;       // row-tile 0..3
    const int fh  = wv & 1;        // n-half 0..1
    const unsigned short* ap = &s_h[1][(twv * 16 + l15) * HS + k0l];
    f16x8 A0 = *(const f16x8*)ap;
    f16x8 A1 = *(const f16x8*)(ap + 32);
    int n = fh * 16 + l15;
    f16x8 Bf0 = cvt8(&W1[n * 64 + k0l]);          // global, L2-hot
    f16x8 Bf1 = cvt8(&W1[n * 64 + 32 + k0l]);
    float bb = b1[n];
    f32x4 accf = (f32x4){bb, bb, bb, bb};
    NOPS_PRE();
    MFMA(accf, A0, Bf0);
    MFMA(accf, A1, Bf1);
    NOPS_POST();
    float* hid = &s_x[0][0];   // [64][36] f32 (x buffers dead)
    #pragma unroll
    for (int r = 0; r < 4; ++r)
      hid[(twv * 16 + lg * 4 + r) * 36 + fh * 16 + l15] = fmaxf(accf[r], 0.f);
  }
  __syncthreads();
  if (tid < RB) {
    const float* hid = &s_x[0][0];
    float a = b2[0];
    #pragma unroll
    for (int kq = 0; kq < 8; ++kq) {
      float4 hv = *(const float4*)&hid[tid * 36 + kq * 4];
      float4 wv4 = *(const float4*)&W2[kq * 4];
      a += hv.x * wv4.x + hv.y * wv4.y + hv.z * wv4.z + hv.w * wv4.w;
    }
    out[blk * RB + tid] = a;
  }
}

extern "C" void kernel_launch(void* const* d_in, const int* in_sizes, int n_in,
                              void* d_out, int out_size, void* d_ws, size_t ws_size,
                              hipStream_t stream) {
  const float* x    = (const float*)d_in[0];
  const float* Wih0 = (const float*)d_in[1];
  const float* Whh0 = (const float*)d_in[2];
  const float* bih0 = (const float*)d_in[3];
  const float* bhh0 = (const float*)d_in[4];
  const float* Wih1 = (const float*)d_in[5];
  const float* Whh1 = (const float*)d_in[6];
  const float* bih1 = (const float*)d_in[7];
  const float* bhh1 = (const float*)d_in[8];
  const float* W1   = (const float*)d_in[9];
  const float* b1   = (const float*)d_in[10];
  const float* W2   = (const float*)d_in[11];
  const float* b2   = (const float*)d_in[12];
  float* out = (float*)d_out;

  const int Btot = in_sizes[0] / (TT * DD);   // 32768
  dim3 grid(Btot / RB), block(NTH);           // 512 blocks = 2/CU, one generation
  lstm2_r19_kernel<<<grid, block, 0, stream>>>(
      x, Wih0, Whh0, bih0, bhh0, Wih1, Whh1, bih1, bhh1, W1, b1, W2, b2, out);
}

// Round 20
// 56.022 us; speedup vs baseline: 1.3726x; 1.2354x over previous
//
#include <hip/hip_runtime.h>

#define TT 7
#define DD 40
#define HH 64
#define RB 128         // rows per block
#define NRT 8          // row-tiles of 16 per wave (processed in pairs)
#define NTH 512        // 8 waves: 0-3 = layer 0 (j-quarters), 4-7 = layer 1
#define HS 72          // u16 stride in h planes (144 B rows -> 2-way-free b128)
#define XP 44          // float stride of x rows in LDS (11 x 16B chunks)
#define L2E 1.44269504088896340736f

typedef _Float16 f16x8 __attribute__((ext_vector_type(8)));
typedef float f32x4 __attribute__((ext_vector_type(4)));

#define MFMA(acc, a, b) acc = __builtin_amdgcn_mfma_f32_16x16x32_f16(a, b, acc, 0, 0, 0)

__device__ __forceinline__ float fast_rcp(float x) { return __builtin_amdgcn_rcpf(x); }
__device__ __forceinline__ float ex2(float x) { return __builtin_amdgcn_exp2f(x); }

// Fused LSTM cell epilogue: 5 ex2 + 3 rcp. Gates pre-scaled by log2e (gate2 & c by 2log2e).
__device__ __forceinline__ float lstm_hc(float a0, float a1, float a2, float a3,
                                         float &c) {
  float A = ex2(-a0);
  float E = ex2(a2);
  float F = ex2(-a1);
  float O = ex2(-a3);
  float igg = (E - 1.f) * fast_rcp((1.f + A) * (1.f + E));   // i * g
  float fg  = fast_rcp(1.f + F);                             // f
  c = fg * c + igg;
  float C = ex2(c * (2.f * L2E));
  return (C - 1.f) * fast_rcp((1.f + O) * (1.f + C));        // o * tanh(c)
}

typedef __attribute__((address_space(3))) unsigned lds_u32_t;
typedef const __attribute__((address_space(1))) unsigned glb_u32_t;
__device__ __forceinline__ void gl_lds16(const void* g, void* l) {
  __builtin_amdgcn_global_load_lds((glb_u32_t*)g, (lds_u32_t*)l, 16, 0, 0);
}

__device__ __forceinline__ f16x8 zf() {
  f16x8 r;
  #pragma unroll
  for (int i = 0; i < 8; ++i) r[i] = (_Float16)0.f;
  return r;
}
__device__ __forceinline__ f16x8 cvt8s(const float* p, float s) {
  float4 a = *(const float4*)p, b = *(const float4*)(p + 4);
  f16x8 r;
  r[0] = (_Float16)(a.x * s); r[1] = (_Float16)(a.y * s);
  r[2] = (_Float16)(a.z * s); r[3] = (_Float16)(a.w * s);
  r[4] = (_Float16)(b.x * s); r[5] = (_Float16)(b.y * s);
  r[6] = (_Float16)(b.z * s); r[7] = (_Float16)(b.w * s);
  return r;
}
__device__ __forceinline__ f16x8 cvt8(const float* p) {
  float4 a = *(const float4*)p, b = *(const float4*)(p + 4);
  f16x8 r;
  r[0] = (_Float16)a.x; r[1] = (_Float16)a.y; r[2] = (_Float16)a.z; r[3] = (_Float16)a.w;
  r[4] = (_Float16)b.x; r[5] = (_Float16)b.y; r[6] = (_Float16)b.z; r[7] = (_Float16)b.w;
  return r;
}
__device__ __forceinline__ f16x8 pk8(float4 a, float4 b) {
  f16x8 r;
  auto p0 = __builtin_amdgcn_cvt_pkrtz(a.x, a.y);
  auto p1 = __builtin_amdgcn_cvt_pkrtz(a.z, a.w);
  auto p2 = __builtin_amdgcn_cvt_pkrtz(b.x, b.y);
  auto p3 = __builtin_amdgcn_cvt_pkrtz(b.z, b.w);
  r[0] = p0[0]; r[1] = p0[1]; r[2] = p1[0]; r[3] = p1[1];
  r[4] = p2[0]; r[5] = p2[1]; r[6] = p3[0]; r[7] = p3[1];
  return r;
}

__global__ __launch_bounds__(NTH, 2) void lstm2_r20_kernel(
    const float* __restrict__ x,
    const float* __restrict__ Wih0, const float* __restrict__ Whh0,
    const float* __restrict__ bih0, const float* __restrict__ bhh0,
    const float* __restrict__ Wih1, const float* __restrict__ Whh1,
    const float* __restrict__ bih1, const float* __restrict__ bhh1,
    const float* __restrict__ W1, const float* __restrict__ b1,
    const float* __restrict__ W2, const float* __restrict__ b2,
    float* __restrict__ out)
{
  // planes: 0,1 = h1 ping-pong; 2,3 = h2 ping-pong (all f16). 118,784 B total.
  __shared__ __align__(16) unsigned short s_h[4][RB * HS];  // 73728 B
  __shared__ __align__(16) float s_x[2][RB * XP];           // 45056 B (tail: hid f32)

  const int tid = threadIdx.x;
  const int l   = tid & 63;
  const int wv  = tid >> 6;        // 0..7
  const bool L0 = (wv < 4);        // wave role: layer 0 vs layer 1
  const int l15 = l & 15;
  const int lg  = l >> 4;
  const int jj  = (wv & 3) * 16 + l15;
  const int k0l = lg * 8;
  const int blk = blockIdx.x;
  const float* xg = x + (size_t)blk * RB * (TT * DD);

  // ---- x-staging: 1408 chunks of 16B (128 rows x 11; chunk 10 of each row = pad) ----
  const int c0 = tid, c1 = 512 + tid, c2 = 1024 + tid;
  const int r0 = c0 / 11, p0 = c0 - r0 * 11;
  const int r1 = c1 / 11, p1 = c1 - r1 * 11;
  const int r2 = c2 / 11, p2 = c2 - r2 * 11;
  const bool v0 = (p0 < 10), v1 = (p1 < 10), v2 = (c2 < 1408) && (p2 < 10);
  const float* xs0 = xg + r0 * (TT * DD) + p0 * 4;
  const float* xs1 = xg + r1 * (TT * DD) + p1 * 4;
  const float* xs2 = xg + r2 * (TT * DD) + p2 * 4;
  const int d0 = wv * 256, d1 = 2048 + wv * 256, d2 = 4096 + wv * 256; // float offs

  // ---- prologue staging: x[0] ----
  if (v0) gl_lds16(xs0, &s_x[0][d0]);
  if (v1) gl_lds16(xs1, &s_x[0][d1]);
  if (v2) gl_lds16(xs2, &s_x[0][d2]);

  // ---- per-role weight fragments (shared registers): 16 frags = 64 VGPR ----
  f16x8 W[16];
  float biasv[4];
  if (L0) {
    #pragma unroll
    for (int g = 0; g < 4; ++g) {
      const float gs = (g == 2) ? 2.f * L2E : L2E;
      int n = g * 64 + jj;
      W[g]      = cvt8s(&Wih0[n * DD + k0l], gs);
      W[4 + g]  = (lg == 0) ? cvt8s(&Wih0[n * DD + 32], gs) : zf();
      W[8 + g]  = cvt8s(&Whh0[n * HH + k0l], gs);
      W[12 + g] = cvt8s(&Whh0[n * HH + 32 + k0l], gs);
      biasv[g] = (bih0[n] + bhh0[n]) * gs;
    }
  } else {
    #pragma unroll
    for (int g = 0; g < 4; ++g) {
      const float gs = (g == 2) ? 2.f * L2E : L2E;
      int n = g * 64 + jj;
      W[g]      = cvt8s(&Wih1[n * HH + k0l], gs);
      W[4 + g]  = cvt8s(&Wih1[n * HH + 32 + k0l], gs);
      W[8 + g]  = cvt8s(&Whh1[n * HH + k0l], gs);
      W[12 + g] = cvt8s(&Whh1[n * HH + 32 + k0l], gs);
      biasv[g] = (bih1[n] + bhh1[n]) * gs;
    }
  }

  float cst[NRT][4];
  #pragma unroll
  for (int rt = 0; rt < NRT; ++rt)
    #pragma unroll
    for (int r = 0; r < 4; ++r) cst[rt][r] = 0.f;

  __syncthreads();   // x[0] staged (vmcnt drained at barrier)

  #pragma unroll 1
  for (int s = 0; s < TT; ++s) {
    if (s) __syncthreads();
    if (s < TT - 1) {          // all threads stage x[s+1]
      float* xd = &s_x[(s + 1) & 1][0];
      const int so = (s + 1) * DD;
      if (v0) gl_lds16(xs0 + so, xd + d0);
      if (v1) gl_lds16(xs1 + so, xd + d1);
      if (v2) gl_lds16(xs2 + so, xd + d2);
    }
    const int p1r = (s - 1) & 1;

    if (L0) {
      // ---- layer 0: h1[s], tiles in PAIRS for cross-tile ILP ----
      const float* xb = &s_x[s & 1][0];
      #pragma unroll
      for (int rp = 0; rp < NRT / 2; ++rp) {
        const int arowA = (2 * rp)     * 16 + l15;
        const int arowB = (2 * rp + 1) * 16 + l15;
        const float* xrA = xb + arowA * XP;
        const float* xrB = xb + arowB * XP;
        f16x8 xhA = pk8(*(const float4*)(xrA + k0l), *(const float4*)(xrA + k0l + 4));
        f16x8 xhB = pk8(*(const float4*)(xrB + k0l), *(const float4*)(xrB + k0l + 4));
        f16x8 xmA = xhA, xmB = xhB;
        if (lg == 0) {
          xmA = pk8(*(const float4*)(xrA + 32), *(const float4*)(xrA + 36));
          xmB = pk8(*(const float4*)(xrB + 32), *(const float4*)(xrB + 36));
        }

        f32x4 accA[4], accB[4];
        #pragma unroll
        for (int g = 0; g < 4; ++g) {
          accA[g] = (f32x4){biasv[g], biasv[g], biasv[g], biasv[g]};
          accB[g] = (f32x4){biasv[g], biasv[g], biasv[g], biasv[g]};
        }

        f16x8 hA0, hA1, hB0, hB1;
        if (s) {
          const unsigned short* hpA = &s_h[p1r][arowA * HS + k0l];
          const unsigned short* hpB = &s_h[p1r][arowB * HS + k0l];
          hA0 = *(const f16x8*)hpA; hA1 = *(const f16x8*)(hpA + 32);
          hB0 = *(const f16x8*)hpB; hB1 = *(const f16x8*)(hpB + 32);
        }
        #pragma unroll
        for (int g = 0; g < 4; ++g) MFMA(accA[g], xhA, W[g]);
        #pragma unroll
        for (int g = 0; g < 4; ++g) MFMA(accB[g], xhB, W[g]);
        #pragma unroll
        for (int g = 0; g < 4; ++g) MFMA(accA[g], xmA, W[4 + g]);
        #pragma unroll
        for (int g = 0; g < 4; ++g) MFMA(accB[g], xmB, W[4 + g]);
        if (s) {
          #pragma unroll
          for (int g = 0; g < 4; ++g) MFMA(accA[g], hA0, W[8 + g]);
          #pragma unroll
          for (int g = 0; g < 4; ++g) MFMA(accB[g], hB0, W[8 + g]);
          #pragma unroll
          for (int g = 0; g < 4; ++g) MFMA(accA[g], hA1, W[12 + g]);
          #pragma unroll
          for (int g = 0; g < 4; ++g) MFMA(accB[g], hB1, W[12 + g]);
        }

        #pragma unroll
        for (int r = 0; r < 4; ++r) {
          float hA = lstm_hc(accA[0][r], accA[1][r], accA[2][r], accA[3][r],
                             cst[2 * rp][r]);
          float hB = lstm_hc(accB[0][r], accB[1][r], accB[2][r], accB[3][r],
                             cst[2 * rp + 1][r]);
          s_h[s & 1][((2 * rp) * 16 + lg * 4 + r) * HS + jj] =
              __builtin_bit_cast(unsigned short, (_Float16)hA);
          s_h[s & 1][((2 * rp + 1) * 16 + lg * 4 + r) * HS + jj] =
              __builtin_bit_cast(unsigned short, (_Float16)hB);
        }
      }
    } else if (s) {
      // ---- layer 1: h2[s-1], tiles in PAIRS ----
      #pragma unroll
      for (int rp = 0; rp < NRT / 2; ++rp) {
        const int arowA = (2 * rp)     * 16 + l15;
        const int arowB = (2 * rp + 1) * 16 + l15;
        const unsigned short* hpA = &s_h[p1r][arowA * HS + k0l];
        const unsigned short* hpB = &s_h[p1r][arowB * HS + k0l];
        f16x8 hA0 = *(const f16x8*)hpA, hA1 = *(const f16x8*)(hpA + 32);
        f16x8 hB0 = *(const f16x8*)hpB, hB1 = *(const f16x8*)(hpB + 32);

        f32x4 accA[4], accB[4];
        #pragma unroll
        for (int g = 0; g < 4; ++g) {
          accA[g] = (f32x4){biasv[g], biasv[g], biasv[g], biasv[g]};
          accB[g] = (f32x4){biasv[g], biasv[g], biasv[g], biasv[g]};
        }

        f16x8 qA0, qA1, qB0, qB1;
        if (s >= 2) {
          const unsigned short* qpA = &s_h[2 + (s & 1)][arowA * HS + k0l];
          const unsigned short* qpB = &s_h[2 + (s & 1)][arowB * HS + k0l];
          qA0 = *(const f16x8*)qpA; qA1 = *(const f16x8*)(qpA + 32);
          qB0 = *(const f16x8*)qpB; qB1 = *(const f16x8*)(qpB + 32);
        }
        #pragma unroll
        for (int g = 0; g < 4; ++g) MFMA(accA[g], hA0, W[g]);
        #pragma unroll
        for (int g = 0; g < 4; ++g) MFMA(accB[g], hB0, W[g]);
        #pragma unroll
        for (int g = 0; g < 4; ++g) MFMA(accA[g], hA1, W[4 + g]);
        #pragma unroll
        for (int g = 0; g < 4; ++g) MFMA(accB[g], hB1, W[4 + g]);
        if (s >= 2) {
          #pragma unroll
          for (int g = 0; g < 4; ++g) MFMA(accA[g], qA0, W[8 + g]);
          #pragma unroll
          for (int g = 0; g < 4; ++g) MFMA(accB[g], qB0, W[8 + g]);
          #pragma unroll
          for (int g = 0; g < 4; ++g) MFMA(accA[g], qA1, W[12 + g]);
          #pragma unroll
          for (int g = 0; g < 4; ++g) MFMA(accB[g], qB1, W[12 + g]);
        }

        #pragma unroll
        for (int r = 0; r < 4; ++r) {
          float hA = lstm_hc(accA[0][r], accA[1][r], accA[2][r], accA[3][r],
                             cst[2 * rp][r]);
          float hB = lstm_hc(accB[0][r], accB[1][r], accB[2][r], accB[3][r],
                             cst[2 * rp + 1][r]);
          s_h[2 + p1r][((2 * rp) * 16 + lg * 4 + r) * HS + jj] =
              __builtin_bit_cast(unsigned short, (_Float16)hA);
          s_h[2 + p1r][((2 * rp + 1) * 16 + lg * 4 + r) * HS + jj] =
              __builtin_bit_cast(unsigned short, (_Float16)hB);
        }
      }
    }
  }

  // ---- final interval: L1 waves compute h2[6] -> f16 plane 1 ----
  __syncthreads();
  if (!L0) {
    #pragma unroll
    for (int rt = 0; rt < NRT; ++rt) {
      const int arow = rt * 16 + l15;
      const unsigned short* hp = &s_h[0][arow * HS + k0l];   // h1[6] (6&1=0)
      f16x8 h1a = *(const f16x8*)hp;
      f16x8 h1b = *(const f16x8*)(hp + 32);
      const unsigned short* qp = &s_h[3][arow * HS + k0l];   // h2[5] (2+(5&1)=3)
      f16x8 q0 = *(const f16x8*)qp;
      f16x8 q1 = *(const f16x8*)(qp + 32);
      f32x4 acc[4];
      #pragma unroll
      for (int g = 0; g < 4; ++g)
        acc[g] = (f32x4){biasv[g], biasv[g], biasv[g], biasv[g]};
      #pragma unroll
      for (int g = 0; g < 4; ++g) MFMA(acc[g], h1a, W[g]);
      #pragma unroll
      for (int g = 0; g < 4; ++g) MFMA(acc[g], h1b, W[4 + g]);
      #pragma unroll
      for (int g = 0; g < 4; ++g) MFMA(acc[g], q0, W[8 + g]);
      #pragma unroll
      for (int g = 0; g < 4; ++g) MFMA(acc[g], q1, W[12 + g]);
      #pragma unroll
      for (int r = 0; r < 4; ++r) {
        float h = lstm_hc(acc[0][r], acc[1][r], acc[2][r], acc[3][r], cst[rt][r]);
        s_h[1][(rt * 16 + lg * 4 + r) * HS + jj] =
            __builtin_bit_cast(unsigned short, (_Float16)h);
      }
    }
  }
  __syncthreads();

  // ---- FC head via MFMA: hid = relu(h2 @ W1^T + b1); wave wv owns row-tile wv ----
  {
    const unsigned short* ap = &s_h[1][(wv * 16 + l15) * HS + k0l];
    f16x8 A0 = *(const f16x8*)ap;
    f16x8 A1 = *(const f16x8*)(ap + 32);
    f16x8 Bf0[2], Bf1[2];
    f32x4 accf[2];
    #pragma unroll
    for (int f = 0; f < 2; ++f) {
      int n = f * 16 + l15;
      Bf0[f] = cvt8(&W1[n * 64 + k0l]);          // global, L2-hot
      Bf1[f] = cvt8(&W1[n * 64 + 32 + k0l]);
      float bb = b1[n];
      accf[f] = (f32x4){bb, bb, bb, bb};
    }
    #pragma unroll
    for (int f = 0; f < 2; ++f) { MFMA(accf[f], A0, Bf0[f]); MFMA(accf[f], A1, Bf1[f]); }
    float* hid = &s_x[0][0];   // [128][36] f32 (x buffers dead)
    #pragma unroll
    for (int f = 0; f < 2; ++f)
      #pragma unroll
      for (int r = 0; r < 4; ++r)
        hid[(wv * 16 + lg * 4 + r) * 36 + f * 16 + l15] = fmaxf(accf[f][r], 0.f);
  }
  __syncthreads();
  if (tid < RB) {
    const float* hid = &s_x[0][0];
    float a = b2[0];
    #pragma unroll
    for (int kq = 0; kq < 8; ++kq) {
      float4 hv = *(const float4*)&hid[tid * 36 + kq * 4];
      float4 wv4 = *(const float4*)&W2[kq * 4];
      a += hv.x * wv4.x + hv.y * wv4.y + hv.z * wv4.z + hv.w * wv4.w;
    }
    out[blk * RB + tid] = a;
  }
}

extern "C" void kernel_launch(void* const* d_in, const int* in_sizes, int n_in,
                              void* d_out, int out_size, void* d_ws, size_t ws_size,
                              hipStream_t stream) {
  const float* x    = (const float*)d_in[0];
  const float* Wih0 = (const float*)d_in[1];
  const float* Whh0 = (const float*)d_in[2];
  const float* bih0 = (const float*)d_in[3];
  const float* bhh0 = (const float*)d_in[4];
  const float* Wih1 = (const float*)d_in[5];
  const float* Whh1 = (const float*)d_in[6];
  const float* bih1 = (const float*)d_in[7];
  const float* bhh1 = (const float*)d_in[8];
  const float* W1   = (const float*)d_in[9];
  const float* b1   = (const float*)d_in[10];
  const float* W2   = (const float*)d_in[11];
  const float* b2   = (const float*)d_in[12];
  float* out = (float*)d_out;

  const int Btot = in_sizes[0] / (TT * DD);   // 32768
  dim3 grid(Btot / RB), block(NTH);           // 256 blocks = exactly 1 per CU
  lstm2_r20_kernel<<<grid, block, 0, stream>>>(
      x, Wih0, Whh0, bih0, bhh0, Wih1, Whh1, bih1, bhh1, W1, b1, W2, b2, out);
}